// Round 11
// baseline (110.307 us; speedup 1.0000x reference)
//
#include <hip/hip_runtime.h>

#define IN_DIM  3
#define HID_DIM 20
#define OUT_DIM 3
#define N_EXP   5
#define ELEMS   4
#define PAIRS   2
#define BLOCK   256
#define SPAN    (BLOCK * ELEMS)

// d_out layout: mixed [B,3] then gate [B,5], fp32.
// Evidence ladder: R5 packing -10us; R6 unrolled-LDS FAILED; R7/R9 wave-count/
// amortization NEUTRAL; R8 VMEM FAILED but proved ideal 40MB traffic + all
// pipes idle; R10 barrier-free direct I/O best (95.9). Model: per-wave stalls
// on s_load weight batches — SMEM returns OUT-OF-ORDER so every batch needs a
// full lgkmcnt(0) drain (~90 serialized scalar-cache round trips/wave).
// R11: pure-DS rolled weight loop. DS returns IN-ORDER -> compiler can
// pipeline ds_read ahead with lgkmcnt(N); rolled body (~35 insts) kills any
// I-cache pressure; wave-uniform addresses = pure broadcast (0 conflicts);
// one preamble barrier only; R10's direct strided global I/O kept verbatim.

typedef float v2f __attribute__((ext_vector_type(2)));

__global__ __launch_bounds__(BLOCK) void moe_kernel(
    const float* __restrict__ x,
    const float* __restrict__ W1,   // [E, IN, HID]
    const float* __restrict__ b1,   // [E, HID]
    const float* __restrict__ W2,   // [E, HID, OUT]
    const float* __restrict__ b2,   // [E, OUT]
    const float* __restrict__ Wg,   // [IN, E]
    const float* __restrict__ bg,   // [E]
    float* __restrict__ out,
    int B)
{
    __shared__ float4 sW[N_EXP * HID_DIM * 2];  // (w10,w11,w12,b1),(w20,w21,w22,0)

    const int t = threadIdx.x;

    // ---- one-time weight pack into LDS (100 threads), single barrier ----
    if (t < N_EXP * HID_DIM) {
        const int e = t / HID_DIM, j = t % HID_DIM;
        float4 a, w;
        a.x = W1[(e * IN_DIM + 0) * HID_DIM + j];
        a.y = W1[(e * IN_DIM + 1) * HID_DIM + j];
        a.z = W1[(e * IN_DIM + 2) * HID_DIM + j];
        a.w = b1[e * HID_DIM + j];
        w.x = W2[(e * HID_DIM + j) * OUT_DIM + 0];
        w.y = W2[(e * HID_DIM + j) * OUT_DIM + 1];
        w.z = W2[(e * HID_DIM + j) * OUT_DIM + 2];
        w.w = 0.f;
        sW[2 * t]     = a;
        sW[2 * t + 1] = w;
    }
    __syncthreads();

    const long long g = (long long)blockIdx.x * BLOCK + t;   // thread id
    const long long base = 4 * g;                            // first element
    float* __restrict__ mixed_out = out;
    float* __restrict__ gate_out  = out + (long long)B * OUT_DIM;

    if (base + ELEMS <= (long long)B) {
        // ---- 1. x loads: 6 float2 at 48B lane stride (dense over 6 instrs) --
        v2f xp[PAIRS][IN_DIM];   // xp[p][i] = (x[base+2p][i], x[base+2p+1][i])
        {
            const float2* x2 = reinterpret_cast<const float2*>(x + 3 * base);
            #pragma unroll
            for (int p = 0; p < PAIRS; ++p) {
                float2 a = x2[3 * p + 0];
                float2 b = x2[3 * p + 1];
                float2 c = x2[3 * p + 2];
                xp[p][0] = (v2f){a.x, b.y};
                xp[p][1] = (v2f){a.y, c.x};
                xp[p][2] = (v2f){b.x, c.y};
            }
        }

        // ---- 2. gate: softmax(x @ Wg + bg), packed pairs ----
        v2f gatep[PAIRS][N_EXP];
        #pragma unroll
        for (int p = 0; p < PAIRS; ++p) {
            v2f lg[N_EXP];
            v2f s = (v2f){0.f, 0.f};
            #pragma unroll
            for (int e = 0; e < N_EXP; ++e) {
                v2f v = (v2f){bg[e], bg[e]};
                #pragma unroll
                for (int i = 0; i < IN_DIM; ++i) {
                    const float w = Wg[i * N_EXP + e];
                    v = __builtin_elementwise_fma(xp[p][i], (v2f){w, w}, v);
                }
                lg[e] = (v2f){__expf(v.x), __expf(v.y)};
                s += lg[e];
            }
            const v2f inv = (v2f){1.0f / s.x, 1.0f / s.y};
            #pragma unroll
            for (int e = 0; e < N_EXP; ++e) gatep[p][e] = lg[e] * inv;
        }

        // ---- 3. gate stores: 10 float2 at 80B lane stride ----
        {
            float2* g2 = reinterpret_cast<float2*>(gate_out + 5 * base);
            #pragma unroll
            for (int p = 0; p < PAIRS; ++p) {
                g2[5 * p + 0] = make_float2(gatep[p][0].x, gatep[p][1].x);
                g2[5 * p + 1] = make_float2(gatep[p][2].x, gatep[p][3].x);
                g2[5 * p + 2] = make_float2(gatep[p][4].x, gatep[p][0].y);
                g2[5 * p + 3] = make_float2(gatep[p][1].y, gatep[p][2].y);
                g2[5 * p + 4] = make_float2(gatep[p][3].y, gatep[p][4].y);
            }
        }

        // ---- 4. experts: ROLLED j-loop, in-order DS broadcast weights ----
        v2f mix[PAIRS][OUT_DIM];
        #pragma unroll
        for (int p = 0; p < PAIRS; ++p)
            #pragma unroll
            for (int k = 0; k < OUT_DIM; ++k) mix[p][k] = (v2f){0.f, 0.f};

        #pragma unroll
        for (int e = 0; e < N_EXP; ++e) {
            v2f oacc[PAIRS][OUT_DIM];
            #pragma unroll
            for (int p = 0; p < PAIRS; ++p)
                #pragma unroll
                for (int k = 0; k < OUT_DIM; ++k) {
                    const float bk = b2[e * OUT_DIM + k];
                    oacc[p][k] = (v2f){bk, bk};
                }
            #pragma unroll 2
            for (int j = 0; j < HID_DIM; ++j) {
                const float4 a = sW[(e * HID_DIM + j) * 2];      // b128 bcast
                const float4 w = sW[(e * HID_DIM + j) * 2 + 1];  // b128 bcast
                #pragma unroll
                for (int p = 0; p < PAIRS; ++p) {
                    v2f h = __builtin_elementwise_fma(xp[p][2], (v2f){a.z, a.z},
                            __builtin_elementwise_fma(xp[p][1], (v2f){a.y, a.y},
                            __builtin_elementwise_fma(xp[p][0], (v2f){a.x, a.x},
                                                      (v2f){a.w, a.w})));
                    h = __builtin_elementwise_max(h, (v2f){0.f, 0.f});
                    oacc[p][0] = __builtin_elementwise_fma(h, (v2f){w.x, w.x}, oacc[p][0]);
                    oacc[p][1] = __builtin_elementwise_fma(h, (v2f){w.y, w.y}, oacc[p][1]);
                    oacc[p][2] = __builtin_elementwise_fma(h, (v2f){w.z, w.z}, oacc[p][2]);
                }
            }
            #pragma unroll
            for (int p = 0; p < PAIRS; ++p)
                #pragma unroll
                for (int k = 0; k < OUT_DIM; ++k)
                    mix[p][k] = __builtin_elementwise_fma(gatep[p][e], oacc[p][k],
                                                          mix[p][k]);
        }

        // ---- 5. mixed stores: 6 float2 at 48B lane stride ----
        {
            float2* m2 = reinterpret_cast<float2*>(mixed_out + 3 * base);
            #pragma unroll
            for (int p = 0; p < PAIRS; ++p) {
                m2[3 * p + 0] = make_float2(mix[p][0].x, mix[p][1].x);
                m2[3 * p + 1] = make_float2(mix[p][2].x, mix[p][0].y);
                m2[3 * p + 2] = make_float2(mix[p][1].y, mix[p][2].y);
            }
        }
    } else {
        // ---- guarded tail (not taken at B = 1M): per-element scalar ----
        for (int c = 0; c < ELEMS; ++c) {
            const long long bidx = base + c;
            if (bidx >= (long long)B) break;
            float xv[IN_DIM];
            for (int i = 0; i < IN_DIM; ++i) xv[i] = x[bidx * IN_DIM + i];

            float lg[N_EXP]; float s = 0.f;
            for (int e = 0; e < N_EXP; ++e) {
                float v = bg[e];
                for (int i = 0; i < IN_DIM; ++i)
                    v = fmaf(xv[i], Wg[i * N_EXP + e], v);
                v = __expf(v); lg[e] = v; s += v;
            }
            const float inv = 1.0f / s;
            for (int e = 0; e < N_EXP; ++e) lg[e] *= inv;

            float mixv[OUT_DIM] = {0.f, 0.f, 0.f};
            for (int e = 0; e < N_EXP; ++e) {
                float oa[OUT_DIM];
                for (int k = 0; k < OUT_DIM; ++k) oa[k] = b2[e * OUT_DIM + k];
                for (int j = 0; j < HID_DIM; ++j) {
                    const float4 a = sW[(e * HID_DIM + j) * 2];
                    const float4 w = sW[(e * HID_DIM + j) * 2 + 1];
                    float h = fmaf(xv[2], a.z, fmaf(xv[1], a.y, fmaf(xv[0], a.x, a.w)));
                    h = fmaxf(h, 0.f);
                    oa[0] = fmaf(h, w.x, oa[0]);
                    oa[1] = fmaf(h, w.y, oa[1]);
                    oa[2] = fmaf(h, w.z, oa[2]);
                }
                for (int k = 0; k < OUT_DIM; ++k)
                    mixv[k] = fmaf(lg[e], oa[k], mixv[k]);
            }
            for (int k = 0; k < OUT_DIM; ++k)
                mixed_out[bidx * OUT_DIM + k] = mixv[k];
            for (int e = 0; e < N_EXP; ++e)
                gate_out[bidx * N_EXP + e] = lg[e];
        }
    }
}

extern "C" void kernel_launch(void* const* d_in, const int* in_sizes, int n_in,
                              void* d_out, int out_size, void* d_ws, size_t ws_size,
                              hipStream_t stream) {
    const float* x  = (const float*)d_in[0];
    const float* W1 = (const float*)d_in[1];
    const float* b1 = (const float*)d_in[2];
    const float* W2 = (const float*)d_in[3];
    const float* b2 = (const float*)d_in[4];
    const float* Wg = (const float*)d_in[5];
    const float* bg = (const float*)d_in[6];
    float* out = (float*)d_out;

    const int B = in_sizes[0] / IN_DIM;
    const int grid = (B + SPAN - 1) / SPAN;

    moe_kernel<<<grid, BLOCK, 0, stream>>>(x, W1, b1, W2, b2, Wg, bg, out, B);
}